// Round 12
// baseline (192.698 us; speedup 1.0000x reference)
//
#include <hip/hip_runtime.h>
#include <math.h>

#define N_NODES 100000
#define N_EDGES 1600000
#define D 64
#define DOUT 40
#define NBUCK ((N_NODES + 255) / 256)    // 391 buckets of 256 dst-nodes
#define CHUNK 1024                       // edges per prep block (occupancy!)
#define NCHUNK ((N_EDGES + CHUNK - 1) / CHUNK)  // 1563 chunks
#define BCAP 4864                        // bucket region capacity (mean 4096 + 12 sigma)

typedef __attribute__((ext_vector_type(8))) short bf16x8v;   // 8 bf16 (4 VGPRs)
typedef __attribute__((ext_vector_type(4))) float f32x4v;    // MFMA accumulator

__device__ inline float bf2f(unsigned u) {
  union { unsigned i; float f; } v;
  v.i = u << 16;
  return v.f;
}
__device__ inline unsigned f2bf(float f) {
  union { float f; unsigned i; } v;
  v.f = f;
  unsigned r = v.i + 0x7fffu + ((v.i >> 16) & 1u);   // RNE
  return r >> 16;
}
// packed accumulate: two bf16 from one u32 -> float2 +=
__device__ inline void addpk(float2& a, unsigned u) {
  union { unsigned i; float f; } lo, hi;
  lo.i = u << 16;
  hi.i = u & 0xffff0000u;
  a.x += lo.f;
  a.y += hi.f;
}

// ---------------------------------------------------------------------------
// prep_kernel: cvt(x->bf16) + weight prep + single-pass bucket scatter.
// 1024-edge chunks -> 1563 blocks (~76% occupancy vs 19% at 4096).
// Fixed bucket regions (BCAP) with atomic reservation => no hist/scan passes.
// ---------------------------------------------------------------------------
__global__ __launch_bounds__(256) void prep_kernel(
    const float* __restrict__ x, unsigned short* __restrict__ xbf,
    const float* __restrict__ W1l, const float* __restrict__ W1r,
    const float* __restrict__ W2l, const float* __restrict__ W2r,
    const float* __restrict__ b2, unsigned short* __restrict__ Wcat1,
    unsigned short* __restrict__ Wcat2, float* __restrict__ b2p,
    const int* __restrict__ src, const int* __restrict__ dst,
    int* __restrict__ bcnt, unsigned* __restrict__ binned) {
  __shared__ unsigned ent[CHUNK];
  __shared__ unsigned short sbk[CHUNK];
  __shared__ int cnt[512], scn[512], pos[512], base[512];
  int t = threadIdx.x;
  int blk = blockIdx.x;
  int gtid = blk * 256 + t;
  int nth = NCHUNK * 256;

  // ---- P0: x -> bf16 row-major (8 floats/item) ----
  const int n8 = N_NODES * D / 8;
  for (int i = gtid; i < n8; i += nth) {
    const float4* p = reinterpret_cast<const float4*>(x) + (size_t)i * 2;
    float4 a = p[0], b = p[1];
    uint4 o;
    o.x = f2bf(a.x) | (f2bf(a.y) << 16);
    o.y = f2bf(a.z) | (f2bf(a.w) << 16);
    o.z = f2bf(b.x) | (f2bf(b.y) << 16);
    o.w = f2bf(b.z) | (f2bf(b.w) << 16);
    reinterpret_cast<uint4*>(xbf)[i] = o;
  }
  // ---- P1: weight prep (tiny, grid-strided) ----
  const int NW = 64 * 128 + 48 * 128 + 48;
  for (int i = gtid; i < NW; i += nth) {
    if (i < 64 * 128) {
      int o = i >> 7, k = i & 127;
      float v = (k < 64) ? W1l[o * 64 + k] : W1r[o * 64 + (k - 64)];
      Wcat1[i] = (unsigned short)f2bf(v);
    } else if (i < 64 * 128 + 48 * 128) {
      int j = i - 64 * 128;
      int o = j >> 7, k = j & 127;
      float v = (o < DOUT) ? ((k < 64) ? W2l[o * 64 + k] : W2r[o * 64 + (k - 64)]) : 0.0f;
      Wcat2[j] = (unsigned short)f2bf(v);
    } else {
      int j = i - 64 * 128 - 48 * 128;
      b2p[j] = (j < DOUT) ? b2[j] : 0.0f;
    }
  }
  // ---- P2: chunked LDS counting-sort by bucket -> fixed-region binned ----
  cnt[t] = 0; cnt[t + 256] = 0;
  __syncthreads();
  int cbase = blk * CHUNK;
  int cc = min(CHUNK, N_EDGES - cbase);
  unsigned my_e[4];
  int my_b[4];
  int nmine = 0;
#pragma unroll
  for (int i = 0; i < 4; ++i) {
    int li = t + i * 256;
    if (li < cc) {
      int s = src[cbase + li];
      int d = dst[cbase + li];
      int b = d >> 8;
      my_e[nmine] = ((unsigned)(d & 255) << 24) | (unsigned)s;
      my_b[nmine] = b;
      nmine++;
      atomicAdd(&cnt[b], 1);
    }
  }
  __syncthreads();
  scn[t] = cnt[t]; scn[t + 256] = cnt[t + 256];
  __syncthreads();
  for (int off = 1; off < 512; off <<= 1) {
    int v0 = (t >= off) ? scn[t - off] : 0;
    int v1 = scn[t + 256 - off];
    __syncthreads();
    scn[t] += v0; scn[t + 256] += v1;
    __syncthreads();
  }
  pos[t] = scn[t] - cnt[t];
  pos[t + 256] = scn[t + 256] - cnt[t + 256];
  __syncthreads();
  for (int i = 0; i < nmine; ++i) {
    int slot = atomicAdd(&pos[my_b[i]], 1);
    ent[slot] = my_e[i];
    sbk[slot] = (unsigned short)my_b[i];
  }
  __syncthreads();
  // reserve global space per touched bucket
  for (int b = t; b < NBUCK; b += 256)
    if (cnt[b] > 0) base[b] = atomicAdd(&bcnt[b], cnt[b]);
  __syncthreads();
  for (int i = t; i < cc; i += 256) {
    int b = sbk[i];
    int excl = scn[b] - cnt[b];
    binned[(size_t)b * BCAP + base[b] + (i - excl)] = ent[i];
  }
}

// ---------------------------------------------------------------------------
// fine_kernel: per-bucket counting-sort (bucket cached in LDS, single global
// read of binned) -> csr (fixed regions) + per-node rs/re. 512 threads.
// ---------------------------------------------------------------------------
__global__ __launch_bounds__(512) void fine_kernel(
    const unsigned* __restrict__ binned, const int* __restrict__ bcnt,
    int* __restrict__ rs, int* __restrict__ re_, int* __restrict__ csr, int N) {
  __shared__ unsigned ent[BCAP];
  __shared__ int c[256], p[256], pos[256];
  int b = blockIdx.x;
  int t = threadIdx.x;
  int cc = bcnt[b];
  int s0 = b * BCAP;
  if (t < 256) c[t] = 0;
  __syncthreads();
  for (int i = t; i < cc; i += 512) {
    unsigned u = binned[s0 + i];
    ent[i] = u;
    atomicAdd(&c[u >> 24], 1);
  }
  __syncthreads();
  if (t < 256) p[t] = c[t];
  __syncthreads();
  for (int off = 1; off < 256; off <<= 1) {
    int v = 0;
    if (t < 256 && t >= off) v = p[t - off];
    __syncthreads();
    if (t < 256) p[t] += v;
    __syncthreads();
  }
  if (t < 256) {
    int excl = p[t] - c[t];
    int node = b * 256 + t;
    if (node < N) {
      rs[node] = s0 + excl;
      re_[node] = s0 + excl + c[t];
    }
    pos[t] = excl;
  }
  __syncthreads();
  for (int i = t; i < cc; i += 512) {
    unsigned u = ent[i];
    int slot = atomicAdd(&pos[u >> 24], 1);
    csr[s0 + slot] = (int)(u & 0xFFFFFFu);
  }
}

// ---------------------------------------------------------------------------
// Aggregation (R8 structure): one wave per node, zero LDS. 8 groups x 8
// lanes; lane loads uint4 = 8 bf16 feats (16B); x2 unroll. float2 packed
// accumulate. Fold shfl_xor(8,16,32); lane (g,t) writes feature t*8+g.
// ---------------------------------------------------------------------------
__global__ __launch_bounds__(256) void agg_kernel(
    const unsigned short* __restrict__ feat, const int* __restrict__ rs,
    const int* __restrict__ re_, const int* __restrict__ csr,
    unsigned short* __restrict__ msbf, int N) {
  int wid = (blockIdx.x * 256 + threadIdx.x) >> 6;
  if (wid >= N) return;
  int lane = threadIdx.x & 63;
  int g = lane >> 3;
  int t = lane & 7;
  int s = rs[wid], en = re_[wid];
  float2 acc[4] = {{0.f, 0.f}, {0.f, 0.f}, {0.f, 0.f}, {0.f, 0.f}};
  int e = s + g;
  for (; e + 8 < en; e += 16) {
    int s0 = csr[e];
    int s1 = csr[e + 8];
    uint4 r0 = *reinterpret_cast<const uint4*>(feat + (size_t)s0 * D + t * 8);
    uint4 r1 = *reinterpret_cast<const uint4*>(feat + (size_t)s1 * D + t * 8);
    addpk(acc[0], r0.x); addpk(acc[1], r0.y); addpk(acc[2], r0.z); addpk(acc[3], r0.w);
    addpk(acc[0], r1.x); addpk(acc[1], r1.y); addpk(acc[2], r1.z); addpk(acc[3], r1.w);
  }
  if (e < en) {
    int s0 = csr[e];
    uint4 r0 = *reinterpret_cast<const uint4*>(feat + (size_t)s0 * D + t * 8);
    addpk(acc[0], r0.x); addpk(acc[1], r0.y); addpk(acc[2], r0.z); addpk(acc[3], r0.w);
  }
#pragma unroll
  for (int j = 0; j < 4; ++j) {
    acc[j].x += __shfl_xor(acc[j].x, 8, 64);
    acc[j].y += __shfl_xor(acc[j].y, 8, 64);
    acc[j].x += __shfl_xor(acc[j].x, 16, 64);
    acc[j].y += __shfl_xor(acc[j].y, 16, 64);
    acc[j].x += __shfl_xor(acc[j].x, 32, 64);
    acc[j].y += __shfl_xor(acc[j].y, 32, 64);
  }
  float inv = 1.0f / fmaxf((float)(en - s), 1.0f);
  float v[8] = {acc[0].x, acc[0].y, acc[1].x, acc[1].y,
                acc[2].x, acc[2].y, acc[3].x, acc[3].y};
  float mv = v[0];
#pragma unroll
  for (int j = 1; j < 8; ++j)
    if (g == j) mv = v[j];        // static-index cndmask chain (no scratch)
  msbf[(size_t)wid * D + t * 8 + g] = (unsigned short)f2bf(mv * inv);
}

// ---------------------------------------------------------------------------
// MFMA linear 1: h = relu([ms|x] @ Wcat1^T + b1), one wave per 16-node tile.
// C/D: col=lane&15, row=(lane>>4)*4+reg  [m89-verified].
// ---------------------------------------------------------------------------
__global__ __launch_bounds__(256) void lin1_kernel(
    const unsigned short* __restrict__ xbf, const unsigned short* __restrict__ msbf,
    const unsigned short* __restrict__ Wcat, const float* __restrict__ b1,
    unsigned short* __restrict__ hbf, int N) {
  int wid = (blockIdx.x * 256 + threadIdx.x) >> 6;   // tile id
  int ntiles = N >> 4;                               // 6250
  if (wid >= ntiles) return;
  int lane = threadIdx.x & 63;
  int col = lane & 15;
  int k0 = (lane >> 4) * 8;
  int base = wid * 16;
  const unsigned short* am = msbf + (size_t)(base + col) * D;
  const unsigned short* ax = xbf + (size_t)(base + col) * D;
  bf16x8v a0 = *(const bf16x8v*)(am + k0);
  bf16x8v a1 = *(const bf16x8v*)(am + 32 + k0);
  bf16x8v a2 = *(const bf16x8v*)(ax + k0);
  bf16x8v a3 = *(const bf16x8v*)(ax + 32 + k0);
  f32x4v acc0 = {0.f, 0.f, 0.f, 0.f}, acc1 = acc0, acc2 = acc0, acc3 = acc0;
#define LIN1_CT(CT, ACC)                                                      \
  {                                                                           \
    const unsigned short* w = Wcat + ((CT)*16 + col) * 128 + k0;              \
    bf16x8v b0 = *(const bf16x8v*)(w);                                        \
    bf16x8v b1v = *(const bf16x8v*)(w + 32);                                  \
    bf16x8v b2v = *(const bf16x8v*)(w + 64);                                  \
    bf16x8v b3v = *(const bf16x8v*)(w + 96);                                  \
    ACC = __builtin_amdgcn_mfma_f32_16x16x32_bf16(a0, b0, ACC, 0, 0, 0);      \
    ACC = __builtin_amdgcn_mfma_f32_16x16x32_bf16(a1, b1v, ACC, 0, 0, 0);     \
    ACC = __builtin_amdgcn_mfma_f32_16x16x32_bf16(a2, b2v, ACC, 0, 0, 0);     \
    ACC = __builtin_amdgcn_mfma_f32_16x16x32_bf16(a3, b3v, ACC, 0, 0, 0);     \
  }
  LIN1_CT(0, acc0) LIN1_CT(1, acc1) LIN1_CT(2, acc2) LIN1_CT(3, acc3)
#undef LIN1_CT
  int rbase = (lane >> 4) * 4;
  float bias0 = b1[col], bias1 = b1[16 + col], bias2 = b1[32 + col], bias3 = b1[48 + col];
#pragma unroll
  for (int r = 0; r < 4; ++r) {
    size_t rowoff = (size_t)(base + rbase + r) * D;
    hbf[rowoff + col]      = (unsigned short)f2bf(fmaxf(acc0[r] + bias0, 0.f));
    hbf[rowoff + 16 + col] = (unsigned short)f2bf(fmaxf(acc1[r] + bias1, 0.f));
    hbf[rowoff + 32 + col] = (unsigned short)f2bf(fmaxf(acc2[r] + bias2, 0.f));
    hbf[rowoff + 48 + col] = (unsigned short)f2bf(fmaxf(acc3[r] + bias3, 0.f));
  }
}

// ---------------------------------------------------------------------------
// MFMA linear 2 + log_softmax (48 cols, 40 valid; 16-lane shfl reduction)
// ---------------------------------------------------------------------------
__global__ __launch_bounds__(256) void lin2_kernel(
    const unsigned short* __restrict__ hbf, const unsigned short* __restrict__ msbf,
    const unsigned short* __restrict__ Wcat, const float* __restrict__ b2p,
    float* __restrict__ out, int N) {
  int wid = (blockIdx.x * 256 + threadIdx.x) >> 6;
  int ntiles = N >> 4;
  if (wid >= ntiles) return;
  int lane = threadIdx.x & 63;
  int col = lane & 15;
  int k0 = (lane >> 4) * 8;
  int base = wid * 16;
  const unsigned short* am = msbf + (size_t)(base + col) * D;
  const unsigned short* ah = hbf + (size_t)(base + col) * D;
  bf16x8v a0 = *(const bf16x8v*)(am + k0);
  bf16x8v a1 = *(const bf16x8v*)(am + 32 + k0);
  bf16x8v a2 = *(const bf16x8v*)(ah + k0);
  bf16x8v a3 = *(const bf16x8v*)(ah + 32 + k0);
  f32x4v acc0 = {0.f, 0.f, 0.f, 0.f}, acc1 = acc0, acc2 = acc0;
#define LIN2_CT(CT, ACC)                                                      \
  {                                                                           \
    const unsigned short* w = Wcat + ((CT)*16 + col) * 128 + k0;              \
    bf16x8v b0 = *(const bf16x8v*)(w);                                        \
    bf16x8v b1v = *(const bf16x8v*)(w + 32);                                  \
    bf16x8v b2v = *(const bf16x8v*)(w + 64);                                  \
    bf16x8v b3v = *(const bf16x8v*)(w + 96);                                  \
    ACC = __builtin_amdgcn_mfma_f32_16x16x32_bf16(a0, b0, ACC, 0, 0, 0);      \
    ACC = __builtin_amdgcn_mfma_f32_16x16x32_bf16(a1, b1v, ACC, 0, 0, 0);     \
    ACC = __builtin_amdgcn_mfma_f32_16x16x32_bf16(a2, b2v, ACC, 0, 0, 0);     \
    ACC = __builtin_amdgcn_mfma_f32_16x16x32_bf16(a3, b3v, ACC, 0, 0, 0);     \
  }
  LIN2_CT(0, acc0) LIN2_CT(1, acc1) LIN2_CT(2, acc2)
#undef LIN2_CT
  int rbase = (lane >> 4) * 4;
  float bias0 = b2p[col], bias1 = b2p[16 + col], bias2 = b2p[32 + col];
  bool v2ok = (col < 8);   // cols 32..39 valid only
#pragma unroll
  for (int r = 0; r < 4; ++r) {
    float v0 = acc0[r] + bias0;
    float v1 = acc1[r] + bias1;
    float v2 = v2ok ? (acc2[r] + bias2) : -INFINITY;
    float mx = fmaxf(fmaxf(v0, v1), v2);
    mx = fmaxf(mx, __shfl_xor(mx, 1, 64));
    mx = fmaxf(mx, __shfl_xor(mx, 2, 64));
    mx = fmaxf(mx, __shfl_xor(mx, 4, 64));
    mx = fmaxf(mx, __shfl_xor(mx, 8, 64));
    float sm = expf(v0 - mx) + expf(v1 - mx) + (v2ok ? expf(v2 - mx) : 0.f);
    sm += __shfl_xor(sm, 1, 64);
    sm += __shfl_xor(sm, 2, 64);
    sm += __shfl_xor(sm, 4, 64);
    sm += __shfl_xor(sm, 8, 64);
    float ls = mx + logf(sm);
    size_t rowoff = (size_t)(base + rbase + r) * DOUT;
    out[rowoff + col] = v0 - ls;
    out[rowoff + 16 + col] = v1 - ls;
    if (v2ok) out[rowoff + 32 + col] = v2 - ls;
  }
}

extern "C" void kernel_launch(void* const* d_in, const int* in_sizes, int n_in,
                              void* d_out, int out_size, void* d_ws, size_t ws_size,
                              hipStream_t stream) {
  const float* x   = (const float*)d_in[0];
  const int*   ei  = (const int*)d_in[1];
  const float* W1l = (const float*)d_in[2];
  const float* b1  = (const float*)d_in[3];
  const float* W1r = (const float*)d_in[4];
  const float* W2l = (const float*)d_in[5];
  const float* b2  = (const float*)d_in[6];
  const float* W2r = (const float*)d_in[7];
  float* out = (float*)d_out;

  const int* src = ei;
  const int* dst = ei + N_EDGES;

  // Workspace (~46.5 MB): xbf | hbf | csr(fixed regions) | rs | re | bcnt |
  // scratch(12.8M: binned then ms1) | Wcat1 | Wcat2 | b2p.  ms2 aliases xbf.
  char* ws = (char*)d_ws;
  size_t featB = (size_t)N_NODES * D * sizeof(unsigned short);  // 12.8 MB
  unsigned short* xbf = (unsigned short*)ws;
  unsigned short* hbf = (unsigned short*)(ws + featB);
  int* csr  = (int*)(ws + 2 * featB);                           // NBUCK*BCAP ints (~7.3 MB)
  int* rs   = csr + (size_t)NBUCK * BCAP;
  int* re_  = rs + N_NODES;
  int* bcnt = re_ + N_NODES;
  char* scratch = (char*)(bcnt + NBUCK);
  scratch = (char*)(((uintptr_t)scratch + 15) & ~(uintptr_t)15);
  unsigned* binned     = (unsigned*)scratch;                    // NBUCK*BCAP (~7.3 MB)
  unsigned short* ms1  = (unsigned short*)scratch;              // 12.8 MB (after fine)
  unsigned short* ms2  = xbf;                                   // after lin1
  unsigned short* Wcat1 = (unsigned short*)(scratch + featB);
  unsigned short* Wcat2 = Wcat1 + 64 * 128;
  float* b2p            = (float*)(Wcat2 + 48 * 128);

  const int AGG_BLOCKS = (N_NODES + 3) / 4;       // one wave per node
  const int LIN_BLOCKS = ((N_NODES / 16) + 3) / 4;

  // ---- fused prep: cvt + wcvt + single-pass bucket scatter ----
  hipMemsetAsync(bcnt, 0, NBUCK * sizeof(int), stream);
  prep_kernel<<<NCHUNK, 256, 0, stream>>>(x, xbf, W1l, W1r, W2l, W2r, b2,
                                          Wcat1, Wcat2, b2p, src, dst, bcnt, binned);
  fine_kernel<<<NBUCK, 512, 0, stream>>>(binned, bcnt, rs, re_, csr, N_NODES);

  // ---- layer 1 ----
  agg_kernel<<<AGG_BLOCKS, 256, 0, stream>>>(xbf, rs, re_, csr, ms1, N_NODES);
  lin1_kernel<<<LIN_BLOCKS, 256, 0, stream>>>(xbf, ms1, Wcat1, b1, hbf, N_NODES);

  // ---- layer 2 ----
  agg_kernel<<<AGG_BLOCKS, 256, 0, stream>>>(hbf, rs, re_, csr, ms2, N_NODES);
  lin2_kernel<<<LIN_BLOCKS, 256, 0, stream>>>(hbf, ms2, Wcat2, b2p, out, N_NODES);
}

// Round 13
// 157.738 us; speedup vs baseline: 1.2216x; 1.2216x over previous
//
#include <hip/hip_runtime.h>
#include <math.h>

#define N_NODES 100000
#define N_EDGES 1600000
#define D 64
#define DOUT 40
#define NBUCK ((N_NODES + 255) / 256)    // 391 buckets of 256 dst-nodes
#define CHUNK 4096                       // edges per prep block (write locality!)
#define NCHUNK ((N_EDGES + CHUNK - 1) / CHUNK)  // 391 chunks
#define PTHREADS 512                     // prep block width (8 waves)
#define BCAP 4864                        // bucket region capacity (mean 4096 + 12 sigma)

typedef __attribute__((ext_vector_type(8))) short bf16x8v;   // 8 bf16 (4 VGPRs)
typedef __attribute__((ext_vector_type(4))) float f32x4v;    // MFMA accumulator

__device__ inline float bf2f(unsigned u) {
  union { unsigned i; float f; } v;
  v.i = u << 16;
  return v.f;
}
__device__ inline unsigned f2bf(float f) {
  union { float f; unsigned i; } v;
  v.f = f;
  unsigned r = v.i + 0x7fffu + ((v.i >> 16) & 1u);   // RNE
  return r >> 16;
}
// packed accumulate: two bf16 from one u32 -> float2 +=
__device__ inline void addpk(float2& a, unsigned u) {
  union { unsigned i; float f; } lo, hi;
  lo.i = u << 16;
  hi.i = u & 0xffff0000u;
  a.x += lo.f;
  a.y += hi.f;
}

// ---------------------------------------------------------------------------
// prep_kernel: cvt(x->bf16) + weight prep + single-pass bucket scatter.
// CHUNK=4096 preserves write locality (R12 lesson); 512 threads halve the
// serial per-block loops (insert 16->8, scatter 16->8) and double waves.
// Fixed bucket regions (BCAP) with atomic reservation => no hist/scan passes.
// ---------------------------------------------------------------------------
__global__ __launch_bounds__(PTHREADS) void prep_kernel(
    const float* __restrict__ x, unsigned short* __restrict__ xbf,
    const float* __restrict__ W1l, const float* __restrict__ W1r,
    const float* __restrict__ W2l, const float* __restrict__ W2r,
    const float* __restrict__ b2, unsigned short* __restrict__ Wcat1,
    unsigned short* __restrict__ Wcat2, float* __restrict__ b2p,
    const int* __restrict__ src, const int* __restrict__ dst,
    int* __restrict__ bcnt, unsigned* __restrict__ binned) {
  __shared__ unsigned ent[CHUNK];
  __shared__ unsigned short sbk[CHUNK];
  __shared__ int cnt[512], scn[512], pos[512], base[512];
  int t = threadIdx.x;
  int blk = blockIdx.x;
  int gtid = blk * PTHREADS + t;
  int nth = NCHUNK * PTHREADS;

  // ---- P0: x -> bf16 row-major (8 floats/item) ----
  const int n8 = N_NODES * D / 8;
  for (int i = gtid; i < n8; i += nth) {
    const float4* p = reinterpret_cast<const float4*>(x) + (size_t)i * 2;
    float4 a = p[0], b = p[1];
    uint4 o;
    o.x = f2bf(a.x) | (f2bf(a.y) << 16);
    o.y = f2bf(a.z) | (f2bf(a.w) << 16);
    o.z = f2bf(b.x) | (f2bf(b.y) << 16);
    o.w = f2bf(b.z) | (f2bf(b.w) << 16);
    reinterpret_cast<uint4*>(xbf)[i] = o;
  }
  // ---- P1: weight prep (tiny, grid-strided) ----
  const int NW = 64 * 128 + 48 * 128 + 48;
  for (int i = gtid; i < NW; i += nth) {
    if (i < 64 * 128) {
      int o = i >> 7, k = i & 127;
      float v = (k < 64) ? W1l[o * 64 + k] : W1r[o * 64 + (k - 64)];
      Wcat1[i] = (unsigned short)f2bf(v);
    } else if (i < 64 * 128 + 48 * 128) {
      int j = i - 64 * 128;
      int o = j >> 7, k = j & 127;
      float v = (o < DOUT) ? ((k < 64) ? W2l[o * 64 + k] : W2r[o * 64 + (k - 64)]) : 0.0f;
      Wcat2[j] = (unsigned short)f2bf(v);
    } else {
      int j = i - 64 * 128 - 48 * 128;
      b2p[j] = (j < DOUT) ? b2[j] : 0.0f;
    }
  }
  // ---- P2: chunked LDS counting-sort by bucket -> fixed-region binned ----
  cnt[t] = 0;
  __syncthreads();
  int cbase = blk * CHUNK;
  int cc = min(CHUNK, N_EDGES - cbase);
  unsigned my_e[8];
  int my_b[8];
  int nmine = 0;
#pragma unroll
  for (int i = 0; i < 8; ++i) {
    int li = t + i * PTHREADS;
    if (li < cc) {
      int s = src[cbase + li];
      int d = dst[cbase + li];
      int b = d >> 8;
      my_e[nmine] = ((unsigned)(d & 255) << 24) | (unsigned)s;
      my_b[nmine] = b;
      nmine++;
      atomicAdd(&cnt[b], 1);
    }
  }
  __syncthreads();
  scn[t] = cnt[t];
  __syncthreads();
  for (int off = 1; off < 512; off <<= 1) {
    int v = (t >= off) ? scn[t - off] : 0;
    __syncthreads();
    scn[t] += v;
    __syncthreads();
  }
  pos[t] = scn[t] - cnt[t];
  __syncthreads();
  for (int i = 0; i < nmine; ++i) {
    int slot = atomicAdd(&pos[my_b[i]], 1);
    ent[slot] = my_e[i];
    sbk[slot] = (unsigned short)my_b[i];
  }
  __syncthreads();
  // reserve global space per touched bucket
  for (int b = t; b < NBUCK; b += PTHREADS)
    if (cnt[b] > 0) base[b] = atomicAdd(&bcnt[b], cnt[b]);
  __syncthreads();
  for (int i = t; i < cc; i += PTHREADS) {
    int b = sbk[i];
    int excl = scn[b] - cnt[b];
    binned[(size_t)b * BCAP + base[b] + (i - excl)] = ent[i];
  }
}

// ---------------------------------------------------------------------------
// fine_kernel: per-bucket counting-sort (bucket cached in LDS, single global
// read of binned) -> csr (fixed regions) + per-node rs/re. 512 threads.
// ---------------------------------------------------------------------------
__global__ __launch_bounds__(512) void fine_kernel(
    const unsigned* __restrict__ binned, const int* __restrict__ bcnt,
    int* __restrict__ rs, int* __restrict__ re_, int* __restrict__ csr, int N) {
  __shared__ unsigned ent[BCAP];
  __shared__ int c[256], p[256], pos[256];
  int b = blockIdx.x;
  int t = threadIdx.x;
  int cc = bcnt[b];
  int s0 = b * BCAP;
  if (t < 256) c[t] = 0;
  __syncthreads();
  for (int i = t; i < cc; i += 512) {
    unsigned u = binned[s0 + i];
    ent[i] = u;
    atomicAdd(&c[u >> 24], 1);
  }
  __syncthreads();
  if (t < 256) p[t] = c[t];
  __syncthreads();
  for (int off = 1; off < 256; off <<= 1) {
    int v = 0;
    if (t < 256 && t >= off) v = p[t - off];
    __syncthreads();
    if (t < 256) p[t] += v;
    __syncthreads();
  }
  if (t < 256) {
    int excl = p[t] - c[t];
    int node = b * 256 + t;
    if (node < N) {
      rs[node] = s0 + excl;
      re_[node] = s0 + excl + c[t];
    }
    pos[t] = excl;
  }
  __syncthreads();
  for (int i = t; i < cc; i += 512) {
    unsigned u = ent[i];
    int slot = atomicAdd(&pos[u >> 24], 1);
    csr[s0 + slot] = (int)(u & 0xFFFFFFu);
  }
}

// ---------------------------------------------------------------------------
// Aggregation (R8 structure): one wave per node, zero LDS. 8 groups x 8
// lanes; lane loads uint4 = 8 bf16 feats (16B); x2 unroll. float2 packed
// accumulate. Fold shfl_xor(8,16,32); lane (g,t) writes feature t*8+g.
// ---------------------------------------------------------------------------
__global__ __launch_bounds__(256) void agg_kernel(
    const unsigned short* __restrict__ feat, const int* __restrict__ rs,
    const int* __restrict__ re_, const int* __restrict__ csr,
    unsigned short* __restrict__ msbf, int N) {
  int wid = (blockIdx.x * 256 + threadIdx.x) >> 6;
  if (wid >= N) return;
  int lane = threadIdx.x & 63;
  int g = lane >> 3;
  int t = lane & 7;
  int s = rs[wid], en = re_[wid];
  float2 acc[4] = {{0.f, 0.f}, {0.f, 0.f}, {0.f, 0.f}, {0.f, 0.f}};
  int e = s + g;
  for (; e + 8 < en; e += 16) {
    int s0 = csr[e];
    int s1 = csr[e + 8];
    uint4 r0 = *reinterpret_cast<const uint4*>(feat + (size_t)s0 * D + t * 8);
    uint4 r1 = *reinterpret_cast<const uint4*>(feat + (size_t)s1 * D + t * 8);
    addpk(acc[0], r0.x); addpk(acc[1], r0.y); addpk(acc[2], r0.z); addpk(acc[3], r0.w);
    addpk(acc[0], r1.x); addpk(acc[1], r1.y); addpk(acc[2], r1.z); addpk(acc[3], r1.w);
  }
  if (e < en) {
    int s0 = csr[e];
    uint4 r0 = *reinterpret_cast<const uint4*>(feat + (size_t)s0 * D + t * 8);
    addpk(acc[0], r0.x); addpk(acc[1], r0.y); addpk(acc[2], r0.z); addpk(acc[3], r0.w);
  }
#pragma unroll
  for (int j = 0; j < 4; ++j) {
    acc[j].x += __shfl_xor(acc[j].x, 8, 64);
    acc[j].y += __shfl_xor(acc[j].y, 8, 64);
    acc[j].x += __shfl_xor(acc[j].x, 16, 64);
    acc[j].y += __shfl_xor(acc[j].y, 16, 64);
    acc[j].x += __shfl_xor(acc[j].x, 32, 64);
    acc[j].y += __shfl_xor(acc[j].y, 32, 64);
  }
  float inv = 1.0f / fmaxf((float)(en - s), 1.0f);
  float v[8] = {acc[0].x, acc[0].y, acc[1].x, acc[1].y,
                acc[2].x, acc[2].y, acc[3].x, acc[3].y};
  float mv = v[0];
#pragma unroll
  for (int j = 1; j < 8; ++j)
    if (g == j) mv = v[j];        // static-index cndmask chain (no scratch)
  msbf[(size_t)wid * D + t * 8 + g] = (unsigned short)f2bf(mv * inv);
}

// ---------------------------------------------------------------------------
// MFMA linear 1: h = relu([ms|x] @ Wcat1^T + b1), one wave per 16-node tile.
// C/D: col=lane&15, row=(lane>>4)*4+reg  [m89-verified].
// ---------------------------------------------------------------------------
__global__ __launch_bounds__(256) void lin1_kernel(
    const unsigned short* __restrict__ xbf, const unsigned short* __restrict__ msbf,
    const unsigned short* __restrict__ Wcat, const float* __restrict__ b1,
    unsigned short* __restrict__ hbf, int N) {
  int wid = (blockIdx.x * 256 + threadIdx.x) >> 6;   // tile id
  int ntiles = N >> 4;                               // 6250
  if (wid >= ntiles) return;
  int lane = threadIdx.x & 63;
  int col = lane & 15;
  int k0 = (lane >> 4) * 8;
  int base = wid * 16;
  const unsigned short* am = msbf + (size_t)(base + col) * D;
  const unsigned short* ax = xbf + (size_t)(base + col) * D;
  bf16x8v a0 = *(const bf16x8v*)(am + k0);
  bf16x8v a1 = *(const bf16x8v*)(am + 32 + k0);
  bf16x8v a2 = *(const bf16x8v*)(ax + k0);
  bf16x8v a3 = *(const bf16x8v*)(ax + 32 + k0);
  f32x4v acc0 = {0.f, 0.f, 0.f, 0.f}, acc1 = acc0, acc2 = acc0, acc3 = acc0;
#define LIN1_CT(CT, ACC)                                                      \
  {                                                                           \
    const unsigned short* w = Wcat + ((CT)*16 + col) * 128 + k0;              \
    bf16x8v b0 = *(const bf16x8v*)(w);                                        \
    bf16x8v b1v = *(const bf16x8v*)(w + 32);                                  \
    bf16x8v b2v = *(const bf16x8v*)(w + 64);                                  \
    bf16x8v b3v = *(const bf16x8v*)(w + 96);                                  \
    ACC = __builtin_amdgcn_mfma_f32_16x16x32_bf16(a0, b0, ACC, 0, 0, 0);      \
    ACC = __builtin_amdgcn_mfma_f32_16x16x32_bf16(a1, b1v, ACC, 0, 0, 0);     \
    ACC = __builtin_amdgcn_mfma_f32_16x16x32_bf16(a2, b2v, ACC, 0, 0, 0);     \
    ACC = __builtin_amdgcn_mfma_f32_16x16x32_bf16(a3, b3v, ACC, 0, 0, 0);     \
  }
  LIN1_CT(0, acc0) LIN1_CT(1, acc1) LIN1_CT(2, acc2) LIN1_CT(3, acc3)
#undef LIN1_CT
  int rbase = (lane >> 4) * 4;
  float bias0 = b1[col], bias1 = b1[16 + col], bias2 = b1[32 + col], bias3 = b1[48 + col];
#pragma unroll
  for (int r = 0; r < 4; ++r) {
    size_t rowoff = (size_t)(base + rbase + r) * D;
    hbf[rowoff + col]      = (unsigned short)f2bf(fmaxf(acc0[r] + bias0, 0.f));
    hbf[rowoff + 16 + col] = (unsigned short)f2bf(fmaxf(acc1[r] + bias1, 0.f));
    hbf[rowoff + 32 + col] = (unsigned short)f2bf(fmaxf(acc2[r] + bias2, 0.f));
    hbf[rowoff + 48 + col] = (unsigned short)f2bf(fmaxf(acc3[r] + bias3, 0.f));
  }
}

// ---------------------------------------------------------------------------
// MFMA linear 2 + log_softmax (48 cols, 40 valid; 16-lane shfl reduction)
// ---------------------------------------------------------------------------
__global__ __launch_bounds__(256) void lin2_kernel(
    const unsigned short* __restrict__ hbf, const unsigned short* __restrict__ msbf,
    const unsigned short* __restrict__ Wcat, const float* __restrict__ b2p,
    float* __restrict__ out, int N) {
  int wid = (blockIdx.x * 256 + threadIdx.x) >> 6;
  int ntiles = N >> 4;
  if (wid >= ntiles) return;
  int lane = threadIdx.x & 63;
  int col = lane & 15;
  int k0 = (lane >> 4) * 8;
  int base = wid * 16;
  const unsigned short* am = msbf + (size_t)(base + col) * D;
  const unsigned short* ah = hbf + (size_t)(base + col) * D;
  bf16x8v a0 = *(const bf16x8v*)(am + k0);
  bf16x8v a1 = *(const bf16x8v*)(am + 32 + k0);
  bf16x8v a2 = *(const bf16x8v*)(ah + k0);
  bf16x8v a3 = *(const bf16x8v*)(ah + 32 + k0);
  f32x4v acc0 = {0.f, 0.f, 0.f, 0.f}, acc1 = acc0, acc2 = acc0;
#define LIN2_CT(CT, ACC)                                                      \
  {                                                                           \
    const unsigned short* w = Wcat + ((CT)*16 + col) * 128 + k0;              \
    bf16x8v b0 = *(const bf16x8v*)(w);                                        \
    bf16x8v b1v = *(const bf16x8v*)(w + 32);                                  \
    bf16x8v b2v = *(const bf16x8v*)(w + 64);                                  \
    bf16x8v b3v = *(const bf16x8v*)(w + 96);                                  \
    ACC = __builtin_amdgcn_mfma_f32_16x16x32_bf16(a0, b0, ACC, 0, 0, 0);      \
    ACC = __builtin_amdgcn_mfma_f32_16x16x32_bf16(a1, b1v, ACC, 0, 0, 0);     \
    ACC = __builtin_amdgcn_mfma_f32_16x16x32_bf16(a2, b2v, ACC, 0, 0, 0);     \
    ACC = __builtin_amdgcn_mfma_f32_16x16x32_bf16(a3, b3v, ACC, 0, 0, 0);     \
  }
  LIN2_CT(0, acc0) LIN2_CT(1, acc1) LIN2_CT(2, acc2)
#undef LIN2_CT
  int rbase = (lane >> 4) * 4;
  float bias0 = b2p[col], bias1 = b2p[16 + col], bias2 = b2p[32 + col];
  bool v2ok = (col < 8);   // cols 32..39 valid only
#pragma unroll
  for (int r = 0; r < 4; ++r) {
    float v0 = acc0[r] + bias0;
    float v1 = acc1[r] + bias1;
    float v2 = v2ok ? (acc2[r] + bias2) : -INFINITY;
    float mx = fmaxf(fmaxf(v0, v1), v2);
    mx = fmaxf(mx, __shfl_xor(mx, 1, 64));
    mx = fmaxf(mx, __shfl_xor(mx, 2, 64));
    mx = fmaxf(mx, __shfl_xor(mx, 4, 64));
    mx = fmaxf(mx, __shfl_xor(mx, 8, 64));
    float sm = expf(v0 - mx) + expf(v1 - mx) + (v2ok ? expf(v2 - mx) : 0.f);
    sm += __shfl_xor(sm, 1, 64);
    sm += __shfl_xor(sm, 2, 64);
    sm += __shfl_xor(sm, 4, 64);
    sm += __shfl_xor(sm, 8, 64);
    float ls = mx + logf(sm);
    size_t rowoff = (size_t)(base + rbase + r) * DOUT;
    out[rowoff + col] = v0 - ls;
    out[rowoff + 16 + col] = v1 - ls;
    if (v2ok) out[rowoff + 32 + col] = v2 - ls;
  }
}

extern "C" void kernel_launch(void* const* d_in, const int* in_sizes, int n_in,
                              void* d_out, int out_size, void* d_ws, size_t ws_size,
                              hipStream_t stream) {
  const float* x   = (const float*)d_in[0];
  const int*   ei  = (const int*)d_in[1];
  const float* W1l = (const float*)d_in[2];
  const float* b1  = (const float*)d_in[3];
  const float* W1r = (const float*)d_in[4];
  const float* W2l = (const float*)d_in[5];
  const float* b2  = (const float*)d_in[6];
  const float* W2r = (const float*)d_in[7];
  float* out = (float*)d_out;

  const int* src = ei;
  const int* dst = ei + N_EDGES;

  // Workspace (~46.5 MB): xbf | hbf | csr(fixed regions) | rs | re | bcnt |
  // scratch(12.8M: binned then ms1) | Wcat1 | Wcat2 | b2p.  ms2 aliases xbf.
  char* ws = (char*)d_ws;
  size_t featB = (size_t)N_NODES * D * sizeof(unsigned short);  // 12.8 MB
  unsigned short* xbf = (unsigned short*)ws;
  unsigned short* hbf = (unsigned short*)(ws + featB);
  int* csr  = (int*)(ws + 2 * featB);                           // NBUCK*BCAP ints (~7.3 MB)
  int* rs   = csr + (size_t)NBUCK * BCAP;
  int* re_  = rs + N_NODES;
  int* bcnt = re_ + N_NODES;
  char* scratch = (char*)(bcnt + NBUCK);
  scratch = (char*)(((uintptr_t)scratch + 15) & ~(uintptr_t)15);
  unsigned* binned     = (unsigned*)scratch;                    // NBUCK*BCAP (~7.3 MB)
  unsigned short* ms1  = (unsigned short*)scratch;              // 12.8 MB (after fine)
  unsigned short* ms2  = xbf;                                   // after lin1
  unsigned short* Wcat1 = (unsigned short*)(scratch + featB);
  unsigned short* Wcat2 = Wcat1 + 64 * 128;
  float* b2p            = (float*)(Wcat2 + 48 * 128);

  const int AGG_BLOCKS = (N_NODES + 3) / 4;       // one wave per node
  const int LIN_BLOCKS = ((N_NODES / 16) + 3) / 4;

  // ---- fused prep: cvt + wcvt + single-pass bucket scatter ----
  hipMemsetAsync(bcnt, 0, NBUCK * sizeof(int), stream);
  prep_kernel<<<NCHUNK, PTHREADS, 0, stream>>>(x, xbf, W1l, W1r, W2l, W2r, b2,
                                               Wcat1, Wcat2, b2p, src, dst, bcnt, binned);
  fine_kernel<<<NBUCK, 512, 0, stream>>>(binned, bcnt, rs, re_, csr, N_NODES);

  // ---- layer 1 ----
  agg_kernel<<<AGG_BLOCKS, 256, 0, stream>>>(xbf, rs, re_, csr, ms1, N_NODES);
  lin1_kernel<<<LIN_BLOCKS, 256, 0, stream>>>(xbf, ms1, Wcat1, b1, hbf, N_NODES);

  // ---- layer 2 ----
  agg_kernel<<<AGG_BLOCKS, 256, 0, stream>>>(hbf, rs, re_, csr, ms2, N_NODES);
  lin2_kernel<<<LIN_BLOCKS, 256, 0, stream>>>(hbf, ms2, Wcat2, b2p, out, N_NODES);
}

// Round 14
// 147.099 us; speedup vs baseline: 1.3100x; 1.0723x over previous
//
#include <hip/hip_runtime.h>
#include <math.h>

#define N_NODES 100000
#define N_EDGES 1600000
#define D 64
#define DOUT 40
#define NBUCK ((N_NODES + 255) / 256)    // 391 buckets of 256 dst-nodes
#define CHUNK 4096                       // edges per prep block (write locality!)
#define NCHUNK ((N_EDGES + CHUNK - 1) / CHUNK)  // 391 chunks
#define PTHREADS 512                     // prep block width (8 waves)
#define BCAP 4864                        // bucket region capacity (mean 4096 + 12 sigma)

typedef __attribute__((ext_vector_type(8))) short bf16x8v;   // 8 bf16 (4 VGPRs)
typedef __attribute__((ext_vector_type(4))) float f32x4v;    // MFMA accumulator

__device__ inline float bf2f(unsigned u) {
  union { unsigned i; float f; } v;
  v.i = u << 16;
  return v.f;
}
__device__ inline unsigned f2bf(float f) {
  union { float f; unsigned i; } v;
  v.f = f;
  unsigned r = v.i + 0x7fffu + ((v.i >> 16) & 1u);   // RNE
  return r >> 16;
}
// packed accumulate: two bf16 from one u32 -> float2 +=
__device__ inline void addpk(float2& a, unsigned u) {
  union { unsigned i; float f; } lo, hi;
  lo.i = u << 16;
  hi.i = u & 0xffff0000u;
  a.x += lo.f;
  a.y += hi.f;
}
__device__ inline void addrow4(float2* A, uint4 r) {
  addpk(A[0], r.x); addpk(A[1], r.y); addpk(A[2], r.z); addpk(A[3], r.w);
}

// ---------------------------------------------------------------------------
// prep_kernel: cvt(x->bf16) + weight prep + single-pass bucket scatter.
// CHUNK=4096 preserves write locality (R12 lesson); 512 threads (R13 win).
// ---------------------------------------------------------------------------
__global__ __launch_bounds__(PTHREADS) void prep_kernel(
    const float* __restrict__ x, unsigned short* __restrict__ xbf,
    const float* __restrict__ W1l, const float* __restrict__ W1r,
    const float* __restrict__ W2l, const float* __restrict__ W2r,
    const float* __restrict__ b2, unsigned short* __restrict__ Wcat1,
    unsigned short* __restrict__ Wcat2, float* __restrict__ b2p,
    const int* __restrict__ src, const int* __restrict__ dst,
    int* __restrict__ bcnt, unsigned* __restrict__ binned) {
  __shared__ unsigned ent[CHUNK];
  __shared__ unsigned short sbk[CHUNK];
  __shared__ int cnt[512], scn[512], pos[512], base[512];
  int t = threadIdx.x;
  int blk = blockIdx.x;
  int gtid = blk * PTHREADS + t;
  int nth = NCHUNK * PTHREADS;

  // ---- P0: x -> bf16 row-major (8 floats/item) ----
  const int n8 = N_NODES * D / 8;
  for (int i = gtid; i < n8; i += nth) {
    const float4* p = reinterpret_cast<const float4*>(x) + (size_t)i * 2;
    float4 a = p[0], b = p[1];
    uint4 o;
    o.x = f2bf(a.x) | (f2bf(a.y) << 16);
    o.y = f2bf(a.z) | (f2bf(a.w) << 16);
    o.z = f2bf(b.x) | (f2bf(b.y) << 16);
    o.w = f2bf(b.z) | (f2bf(b.w) << 16);
    reinterpret_cast<uint4*>(xbf)[i] = o;
  }
  // ---- P1: weight prep (tiny, grid-strided) ----
  const int NW = 64 * 128 + 48 * 128 + 48;
  for (int i = gtid; i < NW; i += nth) {
    if (i < 64 * 128) {
      int o = i >> 7, k = i & 127;
      float v = (k < 64) ? W1l[o * 64 + k] : W1r[o * 64 + (k - 64)];
      Wcat1[i] = (unsigned short)f2bf(v);
    } else if (i < 64 * 128 + 48 * 128) {
      int j = i - 64 * 128;
      int o = j >> 7, k = j & 127;
      float v = (o < DOUT) ? ((k < 64) ? W2l[o * 64 + k] : W2r[o * 64 + (k - 64)]) : 0.0f;
      Wcat2[j] = (unsigned short)f2bf(v);
    } else {
      int j = i - 64 * 128 - 48 * 128;
      b2p[j] = (j < DOUT) ? b2[j] : 0.0f;
    }
  }
  // ---- P2: chunked LDS counting-sort by bucket -> fixed-region binned ----
  cnt[t] = 0;
  __syncthreads();
  int cbase = blk * CHUNK;
  int cc = min(CHUNK, N_EDGES - cbase);
  unsigned my_e[8];
  int my_b[8];
  int nmine = 0;
#pragma unroll
  for (int i = 0; i < 8; ++i) {
    int li = t + i * PTHREADS;
    if (li < cc) {
      int s = src[cbase + li];
      int d = dst[cbase + li];
      int b = d >> 8;
      my_e[nmine] = ((unsigned)(d & 255) << 24) | (unsigned)s;
      my_b[nmine] = b;
      nmine++;
      atomicAdd(&cnt[b], 1);
    }
  }
  __syncthreads();
  scn[t] = cnt[t];
  __syncthreads();
  for (int off = 1; off < 512; off <<= 1) {
    int v = (t >= off) ? scn[t - off] : 0;
    __syncthreads();
    scn[t] += v;
    __syncthreads();
  }
  pos[t] = scn[t] - cnt[t];
  __syncthreads();
  for (int i = 0; i < nmine; ++i) {
    int slot = atomicAdd(&pos[my_b[i]], 1);
    ent[slot] = my_e[i];
    sbk[slot] = (unsigned short)my_b[i];
  }
  __syncthreads();
  for (int b = t; b < NBUCK; b += PTHREADS)
    if (cnt[b] > 0) base[b] = atomicAdd(&bcnt[b], cnt[b]);
  __syncthreads();
  for (int i = t; i < cc; i += PTHREADS) {
    int b = sbk[i];
    int excl = scn[b] - cnt[b];
    binned[(size_t)b * BCAP + base[b] + (i - excl)] = ent[i];
  }
}

// ---------------------------------------------------------------------------
// fine_kernel: per-bucket counting-sort -> csr (fixed regions) + rs/re.
// ---------------------------------------------------------------------------
__global__ __launch_bounds__(512) void fine_kernel(
    const unsigned* __restrict__ binned, const int* __restrict__ bcnt,
    int* __restrict__ rs, int* __restrict__ re_, int* __restrict__ csr, int N) {
  __shared__ unsigned ent[BCAP];
  __shared__ int c[256], p[256], pos[256];
  int b = blockIdx.x;
  int t = threadIdx.x;
  int cc = bcnt[b];
  int s0 = b * BCAP;
  if (t < 256) c[t] = 0;
  __syncthreads();
  for (int i = t; i < cc; i += 512) {
    unsigned u = binned[s0 + i];
    ent[i] = u;
    atomicAdd(&c[u >> 24], 1);
  }
  __syncthreads();
  if (t < 256) p[t] = c[t];
  __syncthreads();
  for (int off = 1; off < 256; off <<= 1) {
    int v = 0;
    if (t < 256 && t >= off) v = p[t - off];
    __syncthreads();
    if (t < 256) p[t] += v;
    __syncthreads();
  }
  if (t < 256) {
    int excl = p[t] - c[t];
    int node = b * 256 + t;
    if (node < N) {
      rs[node] = s0 + excl;
      re_[node] = s0 + excl + c[t];
    }
    pos[t] = excl;
  }
  __syncthreads();
  for (int i = t; i < cc; i += 512) {
    unsigned u = ent[i];
    int slot = atomicAdd(&pos[u >> 24], 1);
    csr[s0 + slot] = (int)(u & 0xFFFFFFu);
  }
}

// ---------------------------------------------------------------------------
// Aggregation: TWO nodes per wave for 2x memory-level parallelism.
// Peeled first pair-iteration: 4 independent dwordx4 gathers in flight
// (clamped safe addresses + predicated accumulates, equivalent to the old
// pair-loop + tail for deg <= 16+g). Rare remainders use the original loops.
// ---------------------------------------------------------------------------
__global__ __launch_bounds__(256) void agg_kernel(
    const unsigned short* __restrict__ feat, const int* __restrict__ rs,
    const int* __restrict__ re_, const int* __restrict__ csr,
    unsigned short* __restrict__ msbf, int N) {
  int wv = (blockIdx.x * 256 + threadIdx.x) >> 6;
  int n0 = wv * 2;
  if (n0 >= N) return;
  int n1 = n0 + 1;                 // N even => valid when n0 is
  int lane = threadIdx.x & 63;
  int g = lane >> 3;
  int t = lane & 7;
  int s0 = rs[n0], en0 = re_[n0];
  int s1 = rs[n1], en1 = re_[n1];
  float2 A[4] = {{0.f,0.f},{0.f,0.f},{0.f,0.f},{0.f,0.f}};
  float2 B[4] = {{0.f,0.f},{0.f,0.f},{0.f,0.f},{0.f,0.f}};
  int e0 = s0 + g, e1 = s1 + g;

  // ---- peeled first pair-iteration for BOTH nodes: 4 loads in flight ----
  {
    bool v0a = e0 < en0, v0b = e0 + 8 < en0;
    bool v1a = e1 < en1, v1b = e1 + 8 < en1;
    int q0a = min(e0, max(en0 - 1, 0));
    int q0b = min(e0 + 8, max(en0 - 1, 0));
    int q1a = min(e1, max(en1 - 1, 0));
    int q1b = min(e1 + 8, max(en1 - 1, 0));
    int i0a = min(csr[q0a], N - 1);
    int i0b = min(csr[q0b], N - 1);
    int i1a = min(csr[q1a], N - 1);
    int i1b = min(csr[q1b], N - 1);
    uint4 r0a = *reinterpret_cast<const uint4*>(feat + (size_t)i0a * D + t * 8);
    uint4 r0b = *reinterpret_cast<const uint4*>(feat + (size_t)i0b * D + t * 8);
    uint4 r1a = *reinterpret_cast<const uint4*>(feat + (size_t)i1a * D + t * 8);
    uint4 r1b = *reinterpret_cast<const uint4*>(feat + (size_t)i1b * D + t * 8);
    if (v0a) addrow4(A, r0a);
    if (v0b) addrow4(A, r0b);
    if (v1a) addrow4(B, r1a);
    if (v1b) addrow4(B, r1b);
    e0 += 16;
    e1 += 16;
  }
  // ---- remainder (deg > 16+g): original pair loop + single tail ----
  for (; e0 + 8 < en0; e0 += 16) {
    int i0 = csr[e0];
    int i1 = csr[e0 + 8];
    uint4 r0 = *reinterpret_cast<const uint4*>(feat + (size_t)i0 * D + t * 8);
    uint4 r1 = *reinterpret_cast<const uint4*>(feat + (size_t)i1 * D + t * 8);
    addrow4(A, r0);
    addrow4(A, r1);
  }
  if (e0 < en0) {
    int i0 = csr[e0];
    uint4 r0 = *reinterpret_cast<const uint4*>(feat + (size_t)i0 * D + t * 8);
    addrow4(A, r0);
  }
  for (; e1 + 8 < en1; e1 += 16) {
    int i0 = csr[e1];
    int i1 = csr[e1 + 8];
    uint4 r0 = *reinterpret_cast<const uint4*>(feat + (size_t)i0 * D + t * 8);
    uint4 r1 = *reinterpret_cast<const uint4*>(feat + (size_t)i1 * D + t * 8);
    addrow4(B, r0);
    addrow4(B, r1);
  }
  if (e1 < en1) {
    int i0 = csr[e1];
    uint4 r0 = *reinterpret_cast<const uint4*>(feat + (size_t)i0 * D + t * 8);
    addrow4(B, r0);
  }
  // ---- fold + write both nodes ----
#pragma unroll
  for (int j = 0; j < 4; ++j) {
    A[j].x += __shfl_xor(A[j].x, 8, 64);  A[j].y += __shfl_xor(A[j].y, 8, 64);
    A[j].x += __shfl_xor(A[j].x, 16, 64); A[j].y += __shfl_xor(A[j].y, 16, 64);
    A[j].x += __shfl_xor(A[j].x, 32, 64); A[j].y += __shfl_xor(A[j].y, 32, 64);
    B[j].x += __shfl_xor(B[j].x, 8, 64);  B[j].y += __shfl_xor(B[j].y, 8, 64);
    B[j].x += __shfl_xor(B[j].x, 16, 64); B[j].y += __shfl_xor(B[j].y, 16, 64);
    B[j].x += __shfl_xor(B[j].x, 32, 64); B[j].y += __shfl_xor(B[j].y, 32, 64);
  }
  float inv0 = 1.0f / fmaxf((float)(en0 - s0), 1.0f);
  float inv1 = 1.0f / fmaxf((float)(en1 - s1), 1.0f);
  float va[8] = {A[0].x, A[0].y, A[1].x, A[1].y, A[2].x, A[2].y, A[3].x, A[3].y};
  float vb[8] = {B[0].x, B[0].y, B[1].x, B[1].y, B[2].x, B[2].y, B[3].x, B[3].y};
  float ma = va[0], mb = vb[0];
#pragma unroll
  for (int j = 1; j < 8; ++j) {
    if (g == j) { ma = va[j]; mb = vb[j]; }   // static-index cndmask chain
  }
  msbf[(size_t)n0 * D + t * 8 + g] = (unsigned short)f2bf(ma * inv0);
  msbf[(size_t)n1 * D + t * 8 + g] = (unsigned short)f2bf(mb * inv1);
}

// ---------------------------------------------------------------------------
// MFMA linear 1: h = relu([ms|x] @ Wcat1^T + b1), one wave per 16-node tile.
// C/D: col=lane&15, row=(lane>>4)*4+reg  [m89-verified].
// ---------------------------------------------------------------------------
__global__ __launch_bounds__(256) void lin1_kernel(
    const unsigned short* __restrict__ xbf, const unsigned short* __restrict__ msbf,
    const unsigned short* __restrict__ Wcat, const float* __restrict__ b1,
    unsigned short* __restrict__ hbf, int N) {
  int wid = (blockIdx.x * 256 + threadIdx.x) >> 6;   // tile id
  int ntiles = N >> 4;                               // 6250
  if (wid >= ntiles) return;
  int lane = threadIdx.x & 63;
  int col = lane & 15;
  int k0 = (lane >> 4) * 8;
  int base = wid * 16;
  const unsigned short* am = msbf + (size_t)(base + col) * D;
  const unsigned short* ax = xbf + (size_t)(base + col) * D;
  bf16x8v a0 = *(const bf16x8v*)(am + k0);
  bf16x8v a1 = *(const bf16x8v*)(am + 32 + k0);
  bf16x8v a2 = *(const bf16x8v*)(ax + k0);
  bf16x8v a3 = *(const bf16x8v*)(ax + 32 + k0);
  f32x4v acc0 = {0.f, 0.f, 0.f, 0.f}, acc1 = acc0, acc2 = acc0, acc3 = acc0;
#define LIN1_CT(CT, ACC)                                                      \
  {                                                                           \
    const unsigned short* w = Wcat + ((CT)*16 + col) * 128 + k0;              \
    bf16x8v b0 = *(const bf16x8v*)(w);                                        \
    bf16x8v b1v = *(const bf16x8v*)(w + 32);                                  \
    bf16x8v b2v = *(const bf16x8v*)(w + 64);                                  \
    bf16x8v b3v = *(const bf16x8v*)(w + 96);                                  \
    ACC = __builtin_amdgcn_mfma_f32_16x16x32_bf16(a0, b0, ACC, 0, 0, 0);      \
    ACC = __builtin_amdgcn_mfma_f32_16x16x32_bf16(a1, b1v, ACC, 0, 0, 0);     \
    ACC = __builtin_amdgcn_mfma_f32_16x16x32_bf16(a2, b2v, ACC, 0, 0, 0);     \
    ACC = __builtin_amdgcn_mfma_f32_16x16x32_bf16(a3, b3v, ACC, 0, 0, 0);     \
  }
  LIN1_CT(0, acc0) LIN1_CT(1, acc1) LIN1_CT(2, acc2) LIN1_CT(3, acc3)
#undef LIN1_CT
  int rbase = (lane >> 4) * 4;
  float bias0 = b1[col], bias1 = b1[16 + col], bias2 = b1[32 + col], bias3 = b1[48 + col];
#pragma unroll
  for (int r = 0; r < 4; ++r) {
    size_t rowoff = (size_t)(base + rbase + r) * D;
    hbf[rowoff + col]      = (unsigned short)f2bf(fmaxf(acc0[r] + bias0, 0.f));
    hbf[rowoff + 16 + col] = (unsigned short)f2bf(fmaxf(acc1[r] + bias1, 0.f));
    hbf[rowoff + 32 + col] = (unsigned short)f2bf(fmaxf(acc2[r] + bias2, 0.f));
    hbf[rowoff + 48 + col] = (unsigned short)f2bf(fmaxf(acc3[r] + bias3, 0.f));
  }
}

// ---------------------------------------------------------------------------
// MFMA linear 2 + log_softmax (48 cols, 40 valid; 16-lane shfl reduction)
// ---------------------------------------------------------------------------
__global__ __launch_bounds__(256) void lin2_kernel(
    const unsigned short* __restrict__ hbf, const unsigned short* __restrict__ msbf,
    const unsigned short* __restrict__ Wcat, const float* __restrict__ b2p,
    float* __restrict__ out, int N) {
  int wid = (blockIdx.x * 256 + threadIdx.x) >> 6;
  int ntiles = N >> 4;
  if (wid >= ntiles) return;
  int lane = threadIdx.x & 63;
  int col = lane & 15;
  int k0 = (lane >> 4) * 8;
  int base = wid * 16;
  const unsigned short* am = msbf + (size_t)(base + col) * D;
  const unsigned short* ah = hbf + (size_t)(base + col) * D;
  bf16x8v a0 = *(const bf16x8v*)(am + k0);
  bf16x8v a1 = *(const bf16x8v*)(am + 32 + k0);
  bf16x8v a2 = *(const bf16x8v*)(ah + k0);
  bf16x8v a3 = *(const bf16x8v*)(ah + 32 + k0);
  f32x4v acc0 = {0.f, 0.f, 0.f, 0.f}, acc1 = acc0, acc2 = acc0;
#define LIN2_CT(CT, ACC)                                                      \
  {                                                                           \
    const unsigned short* w = Wcat + ((CT)*16 + col) * 128 + k0;              \
    bf16x8v b0 = *(const bf16x8v*)(w);                                        \
    bf16x8v b1v = *(const bf16x8v*)(w + 32);                                  \
    bf16x8v b2v = *(const bf16x8v*)(w + 64);                                  \
    bf16x8v b3v = *(const bf16x8v*)(w + 96);                                  \
    ACC = __builtin_amdgcn_mfma_f32_16x16x32_bf16(a0, b0, ACC, 0, 0, 0);      \
    ACC = __builtin_amdgcn_mfma_f32_16x16x32_bf16(a1, b1v, ACC, 0, 0, 0);     \
    ACC = __builtin_amdgcn_mfma_f32_16x16x32_bf16(a2, b2v, ACC, 0, 0, 0);     \
    ACC = __builtin_amdgcn_mfma_f32_16x16x32_bf16(a3, b3v, ACC, 0, 0, 0);     \
  }
  LIN2_CT(0, acc0) LIN2_CT(1, acc1) LIN2_CT(2, acc2)
#undef LIN2_CT
  int rbase = (lane >> 4) * 4;
  float bias0 = b2p[col], bias1 = b2p[16 + col], bias2 = b2p[32 + col];
  bool v2ok = (col < 8);   // cols 32..39 valid only
#pragma unroll
  for (int r = 0; r < 4; ++r) {
    float v0 = acc0[r] + bias0;
    float v1 = acc1[r] + bias1;
    float v2 = v2ok ? (acc2[r] + bias2) : -INFINITY;
    float mx = fmaxf(fmaxf(v0, v1), v2);
    mx = fmaxf(mx, __shfl_xor(mx, 1, 64));
    mx = fmaxf(mx, __shfl_xor(mx, 2, 64));
    mx = fmaxf(mx, __shfl_xor(mx, 4, 64));
    mx = fmaxf(mx, __shfl_xor(mx, 8, 64));
    float sm = expf(v0 - mx) + expf(v1 - mx) + (v2ok ? expf(v2 - mx) : 0.f);
    sm += __shfl_xor(sm, 1, 64);
    sm += __shfl_xor(sm, 2, 64);
    sm += __shfl_xor(sm, 4, 64);
    sm += __shfl_xor(sm, 8, 64);
    float ls = mx + logf(sm);
    size_t rowoff = (size_t)(base + rbase + r) * DOUT;
    out[rowoff + col] = v0 - ls;
    out[rowoff + 16 + col] = v1 - ls;
    if (v2ok) out[rowoff + 32 + col] = v2 - ls;
  }
}

extern "C" void kernel_launch(void* const* d_in, const int* in_sizes, int n_in,
                              void* d_out, int out_size, void* d_ws, size_t ws_size,
                              hipStream_t stream) {
  const float* x   = (const float*)d_in[0];
  const int*   ei  = (const int*)d_in[1];
  const float* W1l = (const float*)d_in[2];
  const float* b1  = (const float*)d_in[3];
  const float* W1r = (const float*)d_in[4];
  const float* W2l = (const float*)d_in[5];
  const float* b2  = (const float*)d_in[6];
  const float* W2r = (const float*)d_in[7];
  float* out = (float*)d_out;

  const int* src = ei;
  const int* dst = ei + N_EDGES;

  // Workspace (~46.5 MB): xbf | hbf | csr(fixed regions) | rs | re | bcnt |
  // scratch(12.8M: binned then ms1) | Wcat1 | Wcat2 | b2p.  ms2 aliases xbf.
  char* ws = (char*)d_ws;
  size_t featB = (size_t)N_NODES * D * sizeof(unsigned short);  // 12.8 MB
  unsigned short* xbf = (unsigned short*)ws;
  unsigned short* hbf = (unsigned short*)(ws + featB);
  int* csr  = (int*)(ws + 2 * featB);                           // NBUCK*BCAP ints (~7.3 MB)
  int* rs   = csr + (size_t)NBUCK * BCAP;
  int* re_  = rs + N_NODES;
  int* bcnt = re_ + N_NODES;
  char* scratch = (char*)(bcnt + NBUCK);
  scratch = (char*)(((uintptr_t)scratch + 15) & ~(uintptr_t)15);
  unsigned* binned     = (unsigned*)scratch;                    // NBUCK*BCAP (~7.3 MB)
  unsigned short* ms1  = (unsigned short*)scratch;              // 12.8 MB (after fine)
  unsigned short* ms2  = xbf;                                   // after lin1
  unsigned short* Wcat1 = (unsigned short*)(scratch + featB);
  unsigned short* Wcat2 = Wcat1 + 64 * 128;
  float* b2p            = (float*)(Wcat2 + 48 * 128);

  const int AGG_BLOCKS = (N_NODES + 7) / 8;       // one wave per 2 nodes
  const int LIN_BLOCKS = ((N_NODES / 16) + 3) / 4;

  // ---- fused prep: cvt + wcvt + single-pass bucket scatter ----
  hipMemsetAsync(bcnt, 0, NBUCK * sizeof(int), stream);
  prep_kernel<<<NCHUNK, PTHREADS, 0, stream>>>(x, xbf, W1l, W1r, W2l, W2r, b2,
                                               Wcat1, Wcat2, b2p, src, dst, bcnt, binned);
  fine_kernel<<<NBUCK, 512, 0, stream>>>(binned, bcnt, rs, re_, csr, N_NODES);

  // ---- layer 1 ----
  agg_kernel<<<AGG_BLOCKS, 256, 0, stream>>>(xbf, rs, re_, csr, ms1, N_NODES);
  lin1_kernel<<<LIN_BLOCKS, 256, 0, stream>>>(xbf, ms1, Wcat1, b1, hbf, N_NODES);

  // ---- layer 2 ----
  agg_kernel<<<AGG_BLOCKS, 256, 0, stream>>>(hbf, rs, re_, csr, ms2, N_NODES);
  lin2_kernel<<<LIN_BLOCKS, 256, 0, stream>>>(hbf, ms2, Wcat2, b2p, out, N_NODES);
}

// Round 15
// 141.597 us; speedup vs baseline: 1.3609x; 1.0389x over previous
//
#include <hip/hip_runtime.h>
#include <math.h>

#define N_NODES 100000
#define N_EDGES 1600000
#define D 64
#define DOUT 40
#define NBUCK ((N_NODES + 255) / 256)    // 391 buckets of 256 dst-nodes
#define CHUNK 4096                       // edges per prep block (write locality!)
#define NCHUNK ((N_EDGES + CHUNK - 1) / CHUNK)  // 391 chunks
#define PTHREADS 512                     // prep block width (8 waves)
#define BCAP 4864                        // bucket region capacity (mean 4096 + 12 sigma)

typedef __attribute__((ext_vector_type(8))) short bf16x8v;   // 8 bf16 (4 VGPRs)
typedef __attribute__((ext_vector_type(4))) float f32x4v;    // MFMA accumulator

__device__ inline float bf2f(unsigned u) {
  union { unsigned i; float f; } v;
  v.i = u << 16;
  return v.f;
}
__device__ inline unsigned f2bf(float f) {
  union { float f; unsigned i; } v;
  v.f = f;
  unsigned r = v.i + 0x7fffu + ((v.i >> 16) & 1u);   // RNE
  return r >> 16;
}
// packed accumulate: two bf16 from one u32 -> float2 +=
__device__ inline void addpk(float2& a, unsigned u) {
  union { unsigned i; float f; } lo, hi;
  lo.i = u << 16;
  hi.i = u & 0xffff0000u;
  a.x += lo.f;
  a.y += hi.f;
}
__device__ inline void addrow4(float2* A, uint4 r) {
  addpk(A[0], r.x); addpk(A[1], r.y); addpk(A[2], r.z); addpk(A[3], r.w);
}

// ---------------------------------------------------------------------------
// prep_kernel: cvt(x->bf16) + weight prep + single-pass bucket scatter.
// (R13 structure: CHUNK=4096 write locality, 512 threads)
// ---------------------------------------------------------------------------
__global__ __launch_bounds__(PTHREADS) void prep_kernel(
    const float* __restrict__ x, unsigned short* __restrict__ xbf,
    const float* __restrict__ W1l, const float* __restrict__ W1r,
    const float* __restrict__ W2l, const float* __restrict__ W2r,
    const float* __restrict__ b2, unsigned short* __restrict__ Wcat1,
    unsigned short* __restrict__ Wcat2, float* __restrict__ b2p,
    const int* __restrict__ src, const int* __restrict__ dst,
    int* __restrict__ bcnt, unsigned* __restrict__ binned) {
  __shared__ unsigned ent[CHUNK];
  __shared__ unsigned short sbk[CHUNK];
  __shared__ int cnt[512], scn[512], pos[512], base[512];
  int t = threadIdx.x;
  int blk = blockIdx.x;
  int gtid = blk * PTHREADS + t;
  int nth = NCHUNK * PTHREADS;

  const int n8 = N_NODES * D / 8;
  for (int i = gtid; i < n8; i += nth) {
    const float4* p = reinterpret_cast<const float4*>(x) + (size_t)i * 2;
    float4 a = p[0], b = p[1];
    uint4 o;
    o.x = f2bf(a.x) | (f2bf(a.y) << 16);
    o.y = f2bf(a.z) | (f2bf(a.w) << 16);
    o.z = f2bf(b.x) | (f2bf(b.y) << 16);
    o.w = f2bf(b.z) | (f2bf(b.w) << 16);
    reinterpret_cast<uint4*>(xbf)[i] = o;
  }
  const int NW = 64 * 128 + 48 * 128 + 48;
  for (int i = gtid; i < NW; i += nth) {
    if (i < 64 * 128) {
      int o = i >> 7, k = i & 127;
      float v = (k < 64) ? W1l[o * 64 + k] : W1r[o * 64 + (k - 64)];
      Wcat1[i] = (unsigned short)f2bf(v);
    } else if (i < 64 * 128 + 48 * 128) {
      int j = i - 64 * 128;
      int o = j >> 7, k = j & 127;
      float v = (o < DOUT) ? ((k < 64) ? W2l[o * 64 + k] : W2r[o * 64 + (k - 64)]) : 0.0f;
      Wcat2[j] = (unsigned short)f2bf(v);
    } else {
      int j = i - 64 * 128 - 48 * 128;
      b2p[j] = (j < DOUT) ? b2[j] : 0.0f;
    }
  }
  cnt[t] = 0;
  __syncthreads();
  int cbase = blk * CHUNK;
  int cc = min(CHUNK, N_EDGES - cbase);
  unsigned my_e[8];
  int my_b[8];
  int nmine = 0;
#pragma unroll
  for (int i = 0; i < 8; ++i) {
    int li = t + i * PTHREADS;
    if (li < cc) {
      int s = src[cbase + li];
      int d = dst[cbase + li];
      int b = d >> 8;
      my_e[nmine] = ((unsigned)(d & 255) << 24) | (unsigned)s;
      my_b[nmine] = b;
      nmine++;
      atomicAdd(&cnt[b], 1);
    }
  }
  __syncthreads();
  scn[t] = cnt[t];
  __syncthreads();
  for (int off = 1; off < 512; off <<= 1) {
    int v = (t >= off) ? scn[t - off] : 0;
    __syncthreads();
    scn[t] += v;
    __syncthreads();
  }
  pos[t] = scn[t] - cnt[t];
  __syncthreads();
  for (int i = 0; i < nmine; ++i) {
    int slot = atomicAdd(&pos[my_b[i]], 1);
    ent[slot] = my_e[i];
    sbk[slot] = (unsigned short)my_b[i];
  }
  __syncthreads();
  for (int b = t; b < NBUCK; b += PTHREADS)
    if (cnt[b] > 0) base[b] = atomicAdd(&bcnt[b], cnt[b]);
  __syncthreads();
  for (int i = t; i < cc; i += PTHREADS) {
    int b = sbk[i];
    int excl = scn[b] - cnt[b];
    binned[(size_t)b * BCAP + base[b] + (i - excl)] = ent[i];
  }
}

// ---------------------------------------------------------------------------
// fine_kernel: per-bucket counting-sort -> csr (fixed regions) + rs/re.
// ---------------------------------------------------------------------------
__global__ __launch_bounds__(512) void fine_kernel(
    const unsigned* __restrict__ binned, const int* __restrict__ bcnt,
    int* __restrict__ rs, int* __restrict__ re_, int* __restrict__ csr, int N) {
  __shared__ unsigned ent[BCAP];
  __shared__ int c[256], p[256], pos[256];
  int b = blockIdx.x;
  int t = threadIdx.x;
  int cc = bcnt[b];
  int s0 = b * BCAP;
  if (t < 256) c[t] = 0;
  __syncthreads();
  for (int i = t; i < cc; i += 512) {
    unsigned u = binned[s0 + i];
    ent[i] = u;
    atomicAdd(&c[u >> 24], 1);
  }
  __syncthreads();
  if (t < 256) p[t] = c[t];
  __syncthreads();
  for (int off = 1; off < 256; off <<= 1) {
    int v = 0;
    if (t < 256 && t >= off) v = p[t - off];
    __syncthreads();
    if (t < 256) p[t] += v;
    __syncthreads();
  }
  if (t < 256) {
    int excl = p[t] - c[t];
    int node = b * 256 + t;
    if (node < N) {
      rs[node] = s0 + excl;
      re_[node] = s0 + excl + c[t];
    }
    pos[t] = excl;
  }
  __syncthreads();
  for (int i = t; i < cc; i += 512) {
    unsigned u = ent[i];
    int slot = atomicAdd(&pos[u >> 24], 1);
    csr[s0 + slot] = (int)(u & 0xFFFFFFu);
  }
}

// ---------------------------------------------------------------------------
// AGG phase body (R14-proven): wave aggregates 2 nodes -> lane (g,t) holds
// mean feats t*8+g of both. Returns via ma/mb references.
// ---------------------------------------------------------------------------
__device__ inline void agg2(const unsigned short* __restrict__ feat,
                            const int* __restrict__ rs, const int* __restrict__ re_,
                            const int* __restrict__ csr, int n0, int N,
                            int g, int t, float& ma, float& mb) {
  int n1 = n0 + 1;
  int s0 = rs[n0], en0 = re_[n0];
  int s1 = rs[n1], en1 = re_[n1];
  float2 A[4] = {{0.f,0.f},{0.f,0.f},{0.f,0.f},{0.f,0.f}};
  float2 B[4] = {{0.f,0.f},{0.f,0.f},{0.f,0.f},{0.f,0.f}};
  int e0 = s0 + g, e1 = s1 + g;
  {   // peeled first pair-iteration for BOTH nodes: 4 loads in flight
    bool v0a = e0 < en0, v0b = e0 + 8 < en0;
    bool v1a = e1 < en1, v1b = e1 + 8 < en1;
    int q0a = min(e0, max(en0 - 1, 0));
    int q0b = min(e0 + 8, max(en0 - 1, 0));
    int q1a = min(e1, max(en1 - 1, 0));
    int q1b = min(e1 + 8, max(en1 - 1, 0));
    int i0a = min(csr[q0a], N - 1);
    int i0b = min(csr[q0b], N - 1);
    int i1a = min(csr[q1a], N - 1);
    int i1b = min(csr[q1b], N - 1);
    uint4 r0a = *reinterpret_cast<const uint4*>(feat + (size_t)i0a * D + t * 8);
    uint4 r0b = *reinterpret_cast<const uint4*>(feat + (size_t)i0b * D + t * 8);
    uint4 r1a = *reinterpret_cast<const uint4*>(feat + (size_t)i1a * D + t * 8);
    uint4 r1b = *reinterpret_cast<const uint4*>(feat + (size_t)i1b * D + t * 8);
    if (v0a) addrow4(A, r0a);
    if (v0b) addrow4(A, r0b);
    if (v1a) addrow4(B, r1a);
    if (v1b) addrow4(B, r1b);
    e0 += 16;
    e1 += 16;
  }
  for (; e0 + 8 < en0; e0 += 16) {
    int i0 = csr[e0];
    int i1 = csr[e0 + 8];
    uint4 r0 = *reinterpret_cast<const uint4*>(feat + (size_t)i0 * D + t * 8);
    uint4 r1 = *reinterpret_cast<const uint4*>(feat + (size_t)i1 * D + t * 8);
    addrow4(A, r0);
    addrow4(A, r1);
  }
  if (e0 < en0) {
    int i0 = csr[e0];
    uint4 r0 = *reinterpret_cast<const uint4*>(feat + (size_t)i0 * D + t * 8);
    addrow4(A, r0);
  }
  for (; e1 + 8 < en1; e1 += 16) {
    int i0 = csr[e1];
    int i1 = csr[e1 + 8];
    uint4 r0 = *reinterpret_cast<const uint4*>(feat + (size_t)i0 * D + t * 8);
    uint4 r1 = *reinterpret_cast<const uint4*>(feat + (size_t)i1 * D + t * 8);
    addrow4(B, r0);
    addrow4(B, r1);
  }
  if (e1 < en1) {
    int i0 = csr[e1];
    uint4 r0 = *reinterpret_cast<const uint4*>(feat + (size_t)i0 * D + t * 8);
    addrow4(B, r0);
  }
#pragma unroll
  for (int j = 0; j < 4; ++j) {
    A[j].x += __shfl_xor(A[j].x, 8, 64);  A[j].y += __shfl_xor(A[j].y, 8, 64);
    A[j].x += __shfl_xor(A[j].x, 16, 64); A[j].y += __shfl_xor(A[j].y, 16, 64);
    A[j].x += __shfl_xor(A[j].x, 32, 64); A[j].y += __shfl_xor(A[j].y, 32, 64);
    B[j].x += __shfl_xor(B[j].x, 8, 64);  B[j].y += __shfl_xor(B[j].y, 8, 64);
    B[j].x += __shfl_xor(B[j].x, 16, 64); B[j].y += __shfl_xor(B[j].y, 16, 64);
    B[j].x += __shfl_xor(B[j].x, 32, 64); B[j].y += __shfl_xor(B[j].y, 32, 64);
  }
  float inv0 = 1.0f / fmaxf((float)(en0 - s0), 1.0f);
  float inv1 = 1.0f / fmaxf((float)(en1 - s1), 1.0f);
  float va[8] = {A[0].x, A[0].y, A[1].x, A[1].y, A[2].x, A[2].y, A[3].x, A[3].y};
  float vb[8] = {B[0].x, B[0].y, B[1].x, B[1].y, B[2].x, B[2].y, B[3].x, B[3].y};
  ma = va[0]; mb = vb[0];
#pragma unroll
  for (int j = 1; j < 8; ++j) {
    if (g == j) { ma = va[j]; mb = vb[j]; }   // static-index cndmask chain
  }
  ma *= inv0;
  mb *= inv1;
}

// ---------------------------------------------------------------------------
// Fused layer 1: 512 threads = 8 waves, block owns one 16-node tile.
// Phase A: each wave aggregates 2 nodes -> msL[16][64] (LDS, bf16).
// Phase B: wave 0 does the MFMA lin (A-frags ms from LDS, self from global).
// C/D: col=lane&15, row=(lane>>4)*4+reg [m89-verified].
// ---------------------------------------------------------------------------
__global__ __launch_bounds__(512) void fused1_kernel(
    const unsigned short* __restrict__ xbf, const int* __restrict__ rs,
    const int* __restrict__ re_, const int* __restrict__ csr,
    const unsigned short* __restrict__ Wcat, const float* __restrict__ b1,
    unsigned short* __restrict__ hbf, int N) {
  __shared__ unsigned short msL[16][64];
  int w = threadIdx.x >> 6;
  int lane = threadIdx.x & 63;
  int g = lane >> 3;
  int t = lane & 7;
  int base = blockIdx.x * 16;
  float ma, mb;
  agg2(xbf, rs, re_, csr, base + w * 2, N, g, t, ma, mb);
  msL[w * 2][t * 8 + g] = (unsigned short)f2bf(ma);
  msL[w * 2 + 1][t * 8 + g] = (unsigned short)f2bf(mb);
  __syncthreads();
  if (threadIdx.x < 64) {
    int col = lane & 15;
    int k0 = (lane >> 4) * 8;
    bf16x8v a0 = *(const bf16x8v*)(&msL[col][k0]);
    bf16x8v a1 = *(const bf16x8v*)(&msL[col][32 + k0]);
    const unsigned short* ax = xbf + (size_t)(base + col) * D;
    bf16x8v a2 = *(const bf16x8v*)(ax + k0);
    bf16x8v a3 = *(const bf16x8v*)(ax + 32 + k0);
    f32x4v acc0 = {0.f, 0.f, 0.f, 0.f}, acc1 = acc0, acc2 = acc0, acc3 = acc0;
#define LIN1_CT(CT, ACC)                                                      \
    {                                                                         \
      const unsigned short* wp = Wcat + ((CT)*16 + col) * 128 + k0;           \
      bf16x8v b0 = *(const bf16x8v*)(wp);                                     \
      bf16x8v b1v = *(const bf16x8v*)(wp + 32);                               \
      bf16x8v b2v = *(const bf16x8v*)(wp + 64);                               \
      bf16x8v b3v = *(const bf16x8v*)(wp + 96);                               \
      ACC = __builtin_amdgcn_mfma_f32_16x16x32_bf16(a0, b0, ACC, 0, 0, 0);    \
      ACC = __builtin_amdgcn_mfma_f32_16x16x32_bf16(a1, b1v, ACC, 0, 0, 0);   \
      ACC = __builtin_amdgcn_mfma_f32_16x16x32_bf16(a2, b2v, ACC, 0, 0, 0);   \
      ACC = __builtin_amdgcn_mfma_f32_16x16x32_bf16(a3, b3v, ACC, 0, 0, 0);   \
    }
    LIN1_CT(0, acc0) LIN1_CT(1, acc1) LIN1_CT(2, acc2) LIN1_CT(3, acc3)
#undef LIN1_CT
    int rbase = (lane >> 4) * 4;
    float bias0 = b1[col], bias1 = b1[16 + col], bias2 = b1[32 + col], bias3 = b1[48 + col];
#pragma unroll
    for (int r = 0; r < 4; ++r) {
      size_t rowoff = (size_t)(base + rbase + r) * D;
      hbf[rowoff + col]      = (unsigned short)f2bf(fmaxf(acc0[r] + bias0, 0.f));
      hbf[rowoff + 16 + col] = (unsigned short)f2bf(fmaxf(acc1[r] + bias1, 0.f));
      hbf[rowoff + 32 + col] = (unsigned short)f2bf(fmaxf(acc2[r] + bias2, 0.f));
      hbf[rowoff + 48 + col] = (unsigned short)f2bf(fmaxf(acc3[r] + bias3, 0.f));
    }
  }
}

// ---------------------------------------------------------------------------
// Fused layer 2: agg(hbf) -> LDS; wave 0 does MFMA lin + log_softmax.
// ---------------------------------------------------------------------------
__global__ __launch_bounds__(512) void fused2_kernel(
    const unsigned short* __restrict__ hbf, const int* __restrict__ rs,
    const int* __restrict__ re_, const int* __restrict__ csr,
    const unsigned short* __restrict__ Wcat, const float* __restrict__ b2p,
    float* __restrict__ out, int N) {
  __shared__ unsigned short msL[16][64];
  int w = threadIdx.x >> 6;
  int lane = threadIdx.x & 63;
  int g = lane >> 3;
  int t = lane & 7;
  int base = blockIdx.x * 16;
  float ma, mb;
  agg2(hbf, rs, re_, csr, base + w * 2, N, g, t, ma, mb);
  msL[w * 2][t * 8 + g] = (unsigned short)f2bf(ma);
  msL[w * 2 + 1][t * 8 + g] = (unsigned short)f2bf(mb);
  __syncthreads();
  if (threadIdx.x < 64) {
    int col = lane & 15;
    int k0 = (lane >> 4) * 8;
    bf16x8v a0 = *(const bf16x8v*)(&msL[col][k0]);
    bf16x8v a1 = *(const bf16x8v*)(&msL[col][32 + k0]);
    const unsigned short* ah = hbf + (size_t)(base + col) * D;
    bf16x8v a2 = *(const bf16x8v*)(ah + k0);
    bf16x8v a3 = *(const bf16x8v*)(ah + 32 + k0);
    f32x4v acc0 = {0.f, 0.f, 0.f, 0.f}, acc1 = acc0, acc2 = acc0;
#define LIN2_CT(CT, ACC)                                                      \
    {                                                                         \
      const unsigned short* wp = Wcat + ((CT)*16 + col) * 128 + k0;           \
      bf16x8v b0 = *(const bf16x8v*)(wp);                                     \
      bf16x8v b1v = *(const bf16x8v*)(wp + 32);                               \
      bf16x8v b2v = *(const bf16x8v*)(wp + 64);                               \
      bf16x8v b3v = *(const bf16x8v*)(wp + 96);                               \
      ACC = __builtin_amdgcn_mfma_f32_16x16x32_bf16(a0, b0, ACC, 0, 0, 0);    \
      ACC = __builtin_amdgcn_mfma_f32_16x16x32_bf16(a1, b1v, ACC, 0, 0, 0);   \
      ACC = __builtin_amdgcn_mfma_f32_16x16x32_bf16(a2, b2v, ACC, 0, 0, 0);   \
      ACC = __builtin_amdgcn_mfma_f32_16x16x32_bf16(a3, b3v, ACC, 0, 0, 0);   \
    }
    LIN2_CT(0, acc0) LIN2_CT(1, acc1) LIN2_CT(2, acc2)
#undef LIN2_CT
    int rbase = (lane >> 4) * 4;
    float bias0 = b2p[col], bias1 = b2p[16 + col], bias2 = b2p[32 + col];
    bool v2ok = (col < 8);   // cols 32..39 valid only
#pragma unroll
    for (int r = 0; r < 4; ++r) {
      float v0 = acc0[r] + bias0;
      float v1 = acc1[r] + bias1;
      float v2 = v2ok ? (acc2[r] + bias2) : -INFINITY;
      float mx = fmaxf(fmaxf(v0, v1), v2);
      mx = fmaxf(mx, __shfl_xor(mx, 1, 64));
      mx = fmaxf(mx, __shfl_xor(mx, 2, 64));
      mx = fmaxf(mx, __shfl_xor(mx, 4, 64));
      mx = fmaxf(mx, __shfl_xor(mx, 8, 64));
      float sm = expf(v0 - mx) + expf(v1 - mx) + (v2ok ? expf(v2 - mx) : 0.f);
      sm += __shfl_xor(sm, 1, 64);
      sm += __shfl_xor(sm, 2, 64);
      sm += __shfl_xor(sm, 4, 64);
      sm += __shfl_xor(sm, 8, 64);
      float ls = mx + logf(sm);
      size_t rowoff = (size_t)(base + rbase + r) * DOUT;
      out[rowoff + col] = v0 - ls;
      out[rowoff + 16 + col] = v1 - ls;
      if (v2ok) out[rowoff + 32 + col] = v2 - ls;
    }
  }
}

extern "C" void kernel_launch(void* const* d_in, const int* in_sizes, int n_in,
                              void* d_out, int out_size, void* d_ws, size_t ws_size,
                              hipStream_t stream) {
  const float* x   = (const float*)d_in[0];
  const int*   ei  = (const int*)d_in[1];
  const float* W1l = (const float*)d_in[2];
  const float* b1  = (const float*)d_in[3];
  const float* W1r = (const float*)d_in[4];
  const float* W2l = (const float*)d_in[5];
  const float* b2  = (const float*)d_in[6];
  const float* W2r = (const float*)d_in[7];
  float* out = (float*)d_out;

  const int* src = ei;
  const int* dst = ei + N_EDGES;

  // Workspace: xbf | hbf | csr(fixed regions) | rs | re | bcnt |
  // scratch(binned) | Wcat1 | Wcat2 | b2p.   (ms buffers no longer needed)
  char* ws = (char*)d_ws;
  size_t featB = (size_t)N_NODES * D * sizeof(unsigned short);  // 12.8 MB
  unsigned short* xbf = (unsigned short*)ws;
  unsigned short* hbf = (unsigned short*)(ws + featB);
  int* csr  = (int*)(ws + 2 * featB);                           // NBUCK*BCAP ints (~7.3 MB)
  int* rs   = csr + (size_t)NBUCK * BCAP;
  int* re_  = rs + N_NODES;
  int* bcnt = re_ + N_NODES;
  char* scratch = (char*)(bcnt + NBUCK);
  scratch = (char*)(((uintptr_t)scratch + 15) & ~(uintptr_t)15);
  unsigned* binned      = (unsigned*)scratch;                   // NBUCK*BCAP (~7.3 MB)
  unsigned short* Wcat1 = (unsigned short*)(scratch + (size_t)NBUCK * BCAP * 4);
  unsigned short* Wcat2 = Wcat1 + 64 * 128;
  float* b2p            = (float*)(Wcat2 + 48 * 128);

  const int NTILES = N_NODES / 16;   // 6250 (N % 16 == 0)

  // ---- fused prep: cvt + wcvt + single-pass bucket scatter ----
  hipMemsetAsync(bcnt, 0, NBUCK * sizeof(int), stream);
  prep_kernel<<<NCHUNK, PTHREADS, 0, stream>>>(x, xbf, W1l, W1r, W2l, W2r, b2,
                                               Wcat1, Wcat2, b2p, src, dst, bcnt, binned);
  fine_kernel<<<NBUCK, 512, 0, stream>>>(binned, bcnt, rs, re_, csr, N_NODES);

  // ---- fused layers (agg -> LDS -> MFMA lin) ----
  fused1_kernel<<<NTILES, 512, 0, stream>>>(xbf, rs, re_, csr, Wcat1, b1, hbf, N_NODES);
  fused2_kernel<<<NTILES, 512, 0, stream>>>(hbf, rs, re_, csr, Wcat2, b2p, out, N_NODES);
}